// Round 5
// baseline (2049.425 us; speedup 1.0000x reference)
//
#include <hip/hip_runtime.h>
#include <math.h>

#define N_NODES 500000
#define N_EDGES 4000000
#define FDIM 10   // IN_DIM + HID
#define HID 8

// Dest space: interleaved, dest = 2*col (mi side) or 2*row+1 (mo side).
#define DSPACE (2 * N_NODES)
#define NB 512
#define BSHIFT 11
#define BMASK 2047
#define NB_USED ((DSPACE + BMASK) / 2048)   // 489

// ---------------------------------------------------------------------------
// Fast transcendentals (hw exp2/rcp; error ~1e-6 vs threshold 1.35e-2)
// ---------------------------------------------------------------------------
__device__ __forceinline__ float fast_tanh(float x) {
    float e = __builtin_amdgcn_exp2f(x * 2.885390082f);  // exp(2x)
    return 1.0f - 2.0f * __builtin_amdgcn_rcpf(e + 1.0f);
}
__device__ __forceinline__ float fast_sigmoid(float x) {
    float e = __builtin_amdgcn_exp2f(-1.442695041f * x); // exp(-x)
    return __builtin_amdgcn_rcpf(1.0f + e);
}

// ---------------------------------------------------------------------------
// Input network: hA[n] = tanh(x @ win_w + win_b) (8 floats, 32B row),
//                xB[n] = x (float2, static across iterations)
// ---------------------------------------------------------------------------
__global__ void input_kernel(const float* __restrict__ x,
                             const float* __restrict__ win_w,
                             const float* __restrict__ win_b,
                             float4* __restrict__ hA,      // [N*2]
                             float2* __restrict__ xB) {    // [N]
    int n = blockIdx.x * blockDim.x + threadIdx.x;
    if (n >= N_NODES) return;
    float x0 = x[2 * n], x1 = x[2 * n + 1];
    float h[HID];
#pragma unroll
    for (int j = 0; j < HID; j++)
        h[j] = fast_tanh(x0 * win_w[j] + x1 * win_w[HID + j] + win_b[j]);
    hA[2 * n]     = make_float4(h[0], h[1], h[2], h[3]);
    hA[2 * n + 1] = make_float4(h[4], h[5], h[6], h[7]);
    xB[n] = make_float2(x0, x1);
}

// ---------------------------------------------------------------------------
// K0: bucket histogram, LDS-staged.
// ---------------------------------------------------------------------------
__global__ void bucket_hist_kernel(const int* __restrict__ row,
                                   const int* __restrict__ col,
                                   int* __restrict__ g_cnt) {
    __shared__ int s_cnt[NB];
    int tid = threadIdx.x;
    for (int i = tid; i < NB; i += 256) s_cnt[i] = 0;
    __syncthreads();
    int base = blockIdx.x * 4096;
#pragma unroll
    for (int k = 0; k < 16; k++) {
        int e = base + k * 256 + tid;
        if (e < N_EDGES) {
            int c = col[e], r = row[e];
            atomicAdd(&s_cnt[(2 * c) >> BSHIFT], 1);
            atomicAdd(&s_cnt[(2 * r + 1) >> BSHIFT], 1);
        }
    }
    __syncthreads();
    for (int i = tid; i < NB; i += 256) {
        int v = s_cnt[i];
        if (v) atomicAdd(&g_cnt[i], v);
    }
}

// ---------------------------------------------------------------------------
// K1: exclusive scan of bucket counts (one block of 512 threads).
// ---------------------------------------------------------------------------
__global__ void bucket_scan_kernel(const int* __restrict__ g_cnt,
                                   int* __restrict__ bucket_base,
                                   int* __restrict__ bucket_cur) {
    __shared__ int s[NB];
    int t = threadIdx.x;
    int c = g_cnt[t];
    s[t] = c;
    __syncthreads();
    for (int off = 1; off < NB; off <<= 1) {
        int v = (t >= off) ? s[t - off] : 0;
        __syncthreads();
        s[t] += v;
        __syncthreads();
    }
    int ex = s[t] - c;
    bucket_base[t] = ex;
    bucket_cur[t] = ex;
    if (t == NB - 1) bucket_base[NB] = s[t];
}

// ---------------------------------------------------------------------------
// K2: binning into bucket-ordered staging (LDS), coalesced flush.
// ---------------------------------------------------------------------------
__global__ void bin_kernel(const int* __restrict__ row,
                           const int* __restrict__ col,
                           int* __restrict__ bucket_cur,
                           unsigned int* __restrict__ binned) {
    __shared__ int s_cnt[NB];
    __shared__ int s_start[NB];
    __shared__ int s_cur[NB];
    __shared__ int s_gbase[NB];
    __shared__ unsigned int s_items[8192];
    __shared__ unsigned short s_ibkt[8192];

    int tid = threadIdx.x;
    if (tid < NB) s_cnt[tid] = 0;
    __syncthreads();

    int base = blockIdx.x * 4096;
    int cc[4], rr[4];
#pragma unroll
    for (int k = 0; k < 4; k++) {
        int e = base + k * 1024 + tid;
        bool ok = (e < N_EDGES);
        cc[k] = ok ? col[e] : -1;
        rr[k] = ok ? row[e] : -1;
        if (ok) {
            atomicAdd(&s_cnt[(2 * cc[k]) >> BSHIFT], 1);
            atomicAdd(&s_cnt[(2 * rr[k] + 1) >> BSHIFT], 1);
        }
    }
    __syncthreads();

    if (tid < NB) s_start[tid] = s_cnt[tid];
    __syncthreads();
    for (int off = 1; off < NB; off <<= 1) {
        int v = 0;
        if (tid < NB && tid >= off) v = s_start[tid - off];
        __syncthreads();
        if (tid < NB) s_start[tid] += v;
        __syncthreads();
    }
    if (tid < NB) {
        int ex = s_start[tid] - s_cnt[tid];
        s_start[tid] = ex;
        s_cur[tid] = ex;
    }
    __syncthreads();

#pragma unroll
    for (int k = 0; k < 4; k++) {
        if (cc[k] >= 0) {
            int d0 = 2 * cc[k];
            int b0 = d0 >> BSHIFT;
            int s0 = atomicAdd(&s_cur[b0], 1);
            s_items[s0] = ((unsigned)(d0 & BMASK) << 19) | (unsigned)rr[k];
            s_ibkt[s0] = (unsigned short)b0;
            int d1 = 2 * rr[k] + 1;
            int b1 = d1 >> BSHIFT;
            int s1 = atomicAdd(&s_cur[b1], 1);
            s_items[s1] = ((unsigned)(d1 & BMASK) << 19) | (unsigned)cc[k];
            s_ibkt[s1] = (unsigned short)b1;
        }
    }
    __syncthreads();

    if (tid < NB) s_gbase[tid] = atomicAdd(&bucket_cur[tid], s_cnt[tid]);
    __syncthreads();

    int tot = s_start[NB - 1] + s_cnt[NB - 1];
    for (int s = tid; s < tot; s += 1024) {
        int b = s_ibkt[s];
        int g = s_gbase[b] + (s - s_start[b]);
        binned[g] = s_items[s];
    }
}

// ---------------------------------------------------------------------------
// K3: CSR finalize per bucket, all fine-grained work in LDS.
// ---------------------------------------------------------------------------
__global__ void csr_kernel(const unsigned int* __restrict__ binned,
                           const int* __restrict__ bucket_base,
                           int* __restrict__ offs,
                           int* __restrict__ entries) {
    __shared__ int s_deg[2048];
    __shared__ int s_off[2048];
    __shared__ int s_cur[2048];
    __shared__ int s_pair[1024];

    int t = threadIdx.x;
    int b = blockIdx.x;
    if (b == 0 && t == 0) offs[DSPACE] = 2 * N_EDGES;

    int ebase = bucket_base[b];
    int eend = bucket_base[b + 1];

    s_deg[t] = 0;
    s_deg[t + 1024] = 0;
    __syncthreads();

    for (int p = ebase + t; p < eend; p += 1024)
        atomicAdd(&s_deg[binned[p] >> 19], 1);
    __syncthreads();

    int d0 = s_deg[2 * t], d1 = s_deg[2 * t + 1];
    s_pair[t] = d0 + d1;
    __syncthreads();
    for (int off = 1; off < 1024; off <<= 1) {
        int v = (t >= off) ? s_pair[t - off] : 0;
        __syncthreads();
        s_pair[t] += v;
        __syncthreads();
    }
    int pex = s_pair[t] - (d0 + d1);
    s_off[2 * t] = pex;
    s_off[2 * t + 1] = pex + d0;
    s_cur[2 * t] = pex;
    s_cur[2 * t + 1] = pex + d0;

    int dest0 = b * 2048 + 2 * t;
    if (dest0 < DSPACE) offs[dest0] = ebase + pex;
    if (dest0 + 1 < DSPACE) offs[dest0 + 1] = ebase + pex + d0;
    __syncthreads();

    for (int p = ebase + t; p < eend; p += 1024) {
        unsigned int it = binned[p];
        int dl = it >> 19;
        int other = it & 0x7FFFF;
        int pos = atomicAdd(&s_cur[dl], 1);
        entries[ebase + pos] = other;
    }
}

// ---------------------------------------------------------------------------
// Final edge network -> out  (split-array loads)
// ---------------------------------------------------------------------------
__global__ void edge_kernel(const int* __restrict__ row,
                            const int* __restrict__ col,
                            const float4* __restrict__ hA,   // [N*2]
                            const float2* __restrict__ xB,   // [N]
                            const float* __restrict__ e1_w,
                            const float* __restrict__ e1_b,
                            const float* __restrict__ e2_w,
                            const float* __restrict__ e2_b,
                            float* __restrict__ out) {
    __shared__ float s_e1w[20 * HID];
    __shared__ float s_e1b[HID];
    __shared__ float s_e2w[HID];
    __shared__ float s_e2b;
    int tid = threadIdx.x;
    if (tid < 160) s_e1w[tid] = e1_w[tid];
    else if (tid < 168) s_e1b[tid - 160] = e1_b[tid - 160];
    else if (tid < 176) s_e2w[tid - 168] = e2_w[tid - 168];
    else if (tid == 176) s_e2b = e2_b[0];
    __syncthreads();

    int i = blockIdx.x * blockDim.x + tid;
    if (i >= N_EDGES) return;

    int r = row[i], c = col[i];
    float4 a0 = hA[2 * c], a1 = hA[2 * c + 1];
    float2 ab = xB[c];
    float4 b0 = hA[2 * r], b1 = hA[2 * r + 1];
    float2 bb = xB[r];
    float a[FDIM] = {a0.x, a0.y, a0.z, a0.w, a1.x, a1.y, a1.z, a1.w, ab.x, ab.y};
    float bfull[FDIM] = {b0.x, b0.y, b0.z, b0.w, b1.x, b1.y, b1.z, b1.w, bb.x, bb.y};

    float dot = s_e2b;
#pragma unroll
    for (int j = 0; j < HID; j++) {
        float v = s_e1b[j];
#pragma unroll
        for (int k = 0; k < FDIM; k++) v += a[k] * s_e1w[k * HID + j];
#pragma unroll
        for (int k = 0; k < FDIM; k++) v += bfull[k] * s_e1w[(FDIM + k) * HID + j];
        dot += fast_tanh(v) * s_e2w[j];
    }
    out[i] = fast_sigmoid(dot);
}

// ---------------------------------------------------------------------------
// Fused edge+gather+node network, split arrays, vectorized I/O.
// ---------------------------------------------------------------------------
__global__ void node_kernel(const float4* __restrict__ hA,   // [N*2] (read)
                            const float2* __restrict__ xB,   // [N] (static)
                            const int* __restrict__ offs,    // [D+1]
                            const int* __restrict__ entries, // [2E]
                            const float* __restrict__ e1_w,
                            const float* __restrict__ e1_b,
                            const float* __restrict__ e2_w,
                            const float* __restrict__ e2_b,
                            const float* __restrict__ n1_w,
                            const float* __restrict__ n1_b,
                            const float* __restrict__ n2_w,
                            const float* __restrict__ n2_b,
                            float4* __restrict__ hAnext) {   // [N*2] (write)
    __shared__ float s_e1w[20 * HID];
    __shared__ float s_e1b[HID];
    __shared__ float s_e2w[HID];
    __shared__ float s_e2b;
    __shared__ float s_n1w[30 * HID];
    __shared__ float s_n1b[HID];
    __shared__ float s_n2w[HID * HID];
    __shared__ float s_n2b[HID];
    int tid = threadIdx.x;
    if (tid < 160) s_e1w[tid] = e1_w[tid];
    else if (tid < 168) s_e1b[tid - 160] = e1_b[tid - 160];
    else if (tid < 176) s_e2w[tid - 168] = e2_w[tid - 168];
    else if (tid == 176) s_e2b = e2_b[0];
    if (tid < 240) s_n1w[tid] = n1_w[tid];
    else if (tid < 248) s_n1b[tid - 240] = n1_b[tid - 240];
    if (tid < 64) s_n2w[tid] = n2_w[tid];
    else if (tid < 72) s_n2b[tid - 64] = n2_b[tid - 64];
    __syncthreads();

    int n = blockIdx.x * blockDim.x + tid;
    if (n >= N_NODES) return;

    float4 sa0 = hA[2 * n], sa1 = hA[2 * n + 1];
    float2 sb = xB[n];
    float xn[FDIM] = {sa0.x, sa0.y, sa0.z, sa0.w, sa1.x, sa1.y, sa1.z, sa1.w, sb.x, sb.y};

    float u_self[HID], v_self[HID];
#pragma unroll
    for (int j = 0; j < HID; j++) {
        float u = 0.f, v = 0.f;
#pragma unroll
        for (int k = 0; k < FDIM; k++) {
            u += xn[k] * s_e1w[k * HID + j];
            v += xn[k] * s_e1w[(FDIM + k) * HID + j];
        }
        u_self[j] = u; v_self[j] = v;
    }

    float mi[FDIM], mo[FDIM];
#pragma unroll
    for (int k = 0; k < FDIM; k++) { mi[k] = 0.f; mo[k] = 0.f; }

    int base2 = 2 * n;
    int s0 = offs[base2], e0 = offs[base2 + 1], e1 = offs[base2 + 2];

    // mi: n is col; other = row (uses bottom half of e1_w for other)
    for (int p = s0; p < e0; p++) {
        int o = entries[p];
        float4 q0 = hA[2 * o], q1 = hA[2 * o + 1];
        float2 qb = xB[o];
        float xo[8] = {q0.x, q0.y, q0.z, q0.w, q1.x, q1.y, q1.z, q1.w};
        float d = s_e2b;
#pragma unroll
        for (int j = 0; j < HID; j++) {
            float v = u_self[j] + s_e1b[j];
#pragma unroll
            for (int k = 0; k < 8; k++) v += xo[k] * s_e1w[(FDIM + k) * HID + j];
            v += qb.x * s_e1w[(FDIM + 8) * HID + j] + qb.y * s_e1w[(FDIM + 9) * HID + j];
            d += fast_tanh(v) * s_e2w[j];
        }
        float e = fast_sigmoid(d);
#pragma unroll
        for (int k = 0; k < 8; k++) mi[k] += xo[k] * e;
        mi[8] += qb.x * e; mi[9] += qb.y * e;
    }

    // mo: n is row; other = col (uses top half of e1_w for other)
    for (int p = e0; p < e1; p++) {
        int o = entries[p];
        float4 q0 = hA[2 * o], q1 = hA[2 * o + 1];
        float2 qb = xB[o];
        float xo[8] = {q0.x, q0.y, q0.z, q0.w, q1.x, q1.y, q1.z, q1.w};
        float d = s_e2b;
#pragma unroll
        for (int j = 0; j < HID; j++) {
            float v = v_self[j] + s_e1b[j];
#pragma unroll
            for (int k = 0; k < 8; k++) v += xo[k] * s_e1w[k * HID + j];
            v += qb.x * s_e1w[8 * HID + j] + qb.y * s_e1w[9 * HID + j];
            d += fast_tanh(v) * s_e2w[j];
        }
        float e = fast_sigmoid(d);
#pragma unroll
        for (int k = 0; k < 8; k++) mo[k] += xo[k] * e;
        mo[8] += qb.x * e; mo[9] += qb.y * e;
    }

    float h[HID];
#pragma unroll
    for (int j = 0; j < HID; j++) {
        float v = s_n1b[j];
#pragma unroll
        for (int k = 0; k < FDIM; k++) v += mi[k] * s_n1w[k * HID + j];
#pragma unroll
        for (int k = 0; k < FDIM; k++) v += mo[k] * s_n1w[(FDIM + k) * HID + j];
#pragma unroll
        for (int k = 0; k < FDIM; k++) v += xn[k] * s_n1w[(2 * FDIM + k) * HID + j];
        h[j] = fast_tanh(v);
    }
    float o0[4], o1[4];
#pragma unroll
    for (int j = 0; j < HID; j++) {
        float v = s_n2b[j];
#pragma unroll
        for (int k = 0; k < HID; k++) v += h[k] * s_n2w[k * HID + j];
        if (j < 4) o0[j] = fast_tanh(v); else o1[j - 4] = fast_tanh(v);
    }
    hAnext[2 * n]     = make_float4(o0[0], o0[1], o0[2], o0[3]);
    hAnext[2 * n + 1] = make_float4(o1[0], o1[1], o1[2], o1[3]);
}

// ---------------------------------------------------------------------------
extern "C" void kernel_launch(void* const* d_in, const int* in_sizes, int n_in,
                              void* d_out, int out_size, void* d_ws, size_t ws_size,
                              hipStream_t stream) {
    const float* x      = (const float*)d_in[0];
    const int*   eidx   = (const int*)d_in[1];
    const float* win_w  = (const float*)d_in[2];
    const float* win_b  = (const float*)d_in[3];
    const float* e1_w   = (const float*)d_in[4];
    const float* e1_b   = (const float*)d_in[5];
    const float* e2_w   = (const float*)d_in[6];
    const float* e2_b   = (const float*)d_in[7];
    const float* n1_w   = (const float*)d_in[8];
    const float* n1_b   = (const float*)d_in[9];
    const float* n2_w   = (const float*)d_in[10];
    const float* n2_b   = (const float*)d_in[11];
    float* out = (float*)d_out;

    const int* row = eidx;
    const int* col = eidx + N_EDGES;

    // Workspace layout (~104 MB):
    float4* hA0 = (float4*)d_ws;                             // N*2 float4 = 16 MB
    float4* hA1 = hA0 + 2 * (size_t)N_NODES;                 // 16 MB
    float2* xB  = (float2*)(hA1 + 2 * (size_t)N_NODES);      // 4 MB
    int* offs        = (int*)(xB + (size_t)N_NODES);         // D+1 (+pad)
    int* g_cnt       = offs + DSPACE + 64;                   // 512
    int* bucket_base = g_cnt + NB;                           // 513 (+pad)
    int* bucket_cur  = bucket_base + NB + 64;                // 512
    unsigned int* binned = (unsigned int*)(bucket_cur + NB); // 2E = 32 MB
    int* entries = (int*)(binned + 2 * (size_t)N_EDGES);     // 2E = 32 MB

    const int BLK = 256;
    int node_blocks = (N_NODES + BLK - 1) / BLK;
    int edge_blocks = (N_EDGES + BLK - 1) / BLK;
    int chunk_blocks = (N_EDGES + 4095) / 4096;

    // --- CSR build ---
    hipMemsetAsync(g_cnt, 0, NB * sizeof(int), stream);
    bucket_hist_kernel<<<chunk_blocks, 256, 0, stream>>>(row, col, g_cnt);
    bucket_scan_kernel<<<1, NB, 0, stream>>>(g_cnt, bucket_base, bucket_cur);
    bin_kernel<<<chunk_blocks, 1024, 0, stream>>>(row, col, bucket_cur, binned);
    csr_kernel<<<NB_USED, 1024, 0, stream>>>(binned, bucket_base, offs, entries);

    // --- input network ---
    input_kernel<<<node_blocks, BLK, 0, stream>>>(x, win_w, win_b, hA0, xB);

    // --- message-passing iterations (ping-pong hA) ---
    float4* cur = hA0;
    float4* nxt = hA1;
    for (int it = 0; it < 3; it++) {
        node_kernel<<<node_blocks, BLK, 0, stream>>>(
            cur, xB, offs, entries, e1_w, e1_b, e2_w, e2_b,
            n1_w, n1_b, n2_w, n2_b, nxt);
        float4* t = cur; cur = nxt; nxt = t;
    }

    // --- final edge network -> out ---
    edge_kernel<<<edge_blocks, BLK, 0, stream>>>(
        row, col, cur, xB, e1_w, e1_b, e2_w, e2_b, out);
}

// Round 6
// 2032.452 us; speedup vs baseline: 1.0084x; 1.0084x over previous
//
#include <hip/hip_runtime.h>
#include <math.h>

#define N_NODES 500000
#define N_EDGES 4000000
#define FDIM 10   // IN_DIM + HID
#define HID 8
#define ROWF 16   // floats per padded node row (64 B)

// Dest space: interleaved, dest = 2*col (mi side) or 2*row+1 (mo side).
#define DSPACE (2 * N_NODES)
#define NB 512
#define BSHIFT 11
#define BMASK 2047
#define NB_USED ((DSPACE + BMASK) / 2048)   // 489

#define NODE_BLOCKS ((N_NODES + 255) / 256)     // 1954
#define ROWS_PAD (NODE_BLOCKS * 256)            // 500224

// ---------------------------------------------------------------------------
// Fast transcendentals (hw exp2/rcp; error ~1e-6 vs threshold 1.35e-2)
// ---------------------------------------------------------------------------
__device__ __forceinline__ float fast_tanh(float x) {
    float e = __builtin_amdgcn_exp2f(x * 2.885390082f);  // exp(2x)
    return 1.0f - 2.0f * __builtin_amdgcn_rcpf(e + 1.0f);
}
__device__ __forceinline__ float fast_sigmoid(float x) {
    float e = __builtin_amdgcn_exp2f(-1.442695041f * x); // exp(-x)
    return __builtin_amdgcn_rcpf(1.0f + e);
}

// ---------------------------------------------------------------------------
// Input network: xrow[n] = [tanh(x @ win_w + win_b), x, pad] (64 B row),
// written full-line coalesced via LDS staging.
// ---------------------------------------------------------------------------
__global__ void input_kernel(const float* __restrict__ x,
                             const float* __restrict__ win_w,
                             const float* __restrict__ win_b,
                             float* __restrict__ xrow) {
    __shared__ float s_out[256 * 17];
    int tid = threadIdx.x;
    int n = blockIdx.x * 256 + tid;
    float x0 = 0.f, x1 = 0.f;
    if (n < N_NODES) { x0 = x[2 * n]; x1 = x[2 * n + 1]; }
    int lb = tid * 17;
#pragma unroll
    for (int j = 0; j < HID; j++)
        s_out[lb + j] = fast_tanh(x0 * win_w[j] + x1 * win_w[HID + j] + win_b[j]);
    s_out[lb + 8] = x0;
    s_out[lb + 9] = x1;
#pragma unroll
    for (int j = 10; j < 16; j++) s_out[lb + j] = 0.f;
    __syncthreads();
    float4* dst = (float4*)xrow + (size_t)blockIdx.x * 1024;
    for (int s4 = tid; s4 < 1024; s4 += 256) {
        int fb = s4 * 4, ni = fb >> 4, j = fb & 15;
        dst[s4] = make_float4(s_out[ni * 17 + j], s_out[ni * 17 + j + 1],
                              s_out[ni * 17 + j + 2], s_out[ni * 17 + j + 3]);
    }
}

// ---------------------------------------------------------------------------
// K0: bucket histogram, LDS-staged.
// ---------------------------------------------------------------------------
__global__ void bucket_hist_kernel(const int* __restrict__ row,
                                   const int* __restrict__ col,
                                   int* __restrict__ g_cnt) {
    __shared__ int s_cnt[NB];
    int tid = threadIdx.x;
    for (int i = tid; i < NB; i += 256) s_cnt[i] = 0;
    __syncthreads();
    int base = blockIdx.x * 4096;
#pragma unroll
    for (int k = 0; k < 16; k++) {
        int e = base + k * 256 + tid;
        if (e < N_EDGES) {
            int c = col[e], r = row[e];
            atomicAdd(&s_cnt[(2 * c) >> BSHIFT], 1);
            atomicAdd(&s_cnt[(2 * r + 1) >> BSHIFT], 1);
        }
    }
    __syncthreads();
    for (int i = tid; i < NB; i += 256) {
        int v = s_cnt[i];
        if (v) atomicAdd(&g_cnt[i], v);
    }
}

// ---------------------------------------------------------------------------
// K1: exclusive scan of bucket counts.
// ---------------------------------------------------------------------------
__global__ void bucket_scan_kernel(const int* __restrict__ g_cnt,
                                   int* __restrict__ bucket_base,
                                   int* __restrict__ bucket_cur) {
    __shared__ int s[NB];
    int t = threadIdx.x;
    int c = g_cnt[t];
    s[t] = c;
    __syncthreads();
    for (int off = 1; off < NB; off <<= 1) {
        int v = (t >= off) ? s[t - off] : 0;
        __syncthreads();
        s[t] += v;
        __syncthreads();
    }
    int ex = s[t] - c;
    bucket_base[t] = ex;
    bucket_cur[t] = ex;
    if (t == NB - 1) bucket_base[NB] = s[t];
}

// ---------------------------------------------------------------------------
// K2: binning into bucket-ordered staging (LDS), coalesced flush.
// ---------------------------------------------------------------------------
__global__ void bin_kernel(const int* __restrict__ row,
                           const int* __restrict__ col,
                           int* __restrict__ bucket_cur,
                           unsigned int* __restrict__ binned) {
    __shared__ int s_cnt[NB];
    __shared__ int s_start[NB];
    __shared__ int s_cur[NB];
    __shared__ int s_gbase[NB];
    __shared__ unsigned int s_items[8192];
    __shared__ unsigned short s_ibkt[8192];

    int tid = threadIdx.x;
    if (tid < NB) s_cnt[tid] = 0;
    __syncthreads();

    int base = blockIdx.x * 4096;
    int cc[4], rr[4];
#pragma unroll
    for (int k = 0; k < 4; k++) {
        int e = base + k * 1024 + tid;
        bool ok = (e < N_EDGES);
        cc[k] = ok ? col[e] : -1;
        rr[k] = ok ? row[e] : -1;
        if (ok) {
            atomicAdd(&s_cnt[(2 * cc[k]) >> BSHIFT], 1);
            atomicAdd(&s_cnt[(2 * rr[k] + 1) >> BSHIFT], 1);
        }
    }
    __syncthreads();

    if (tid < NB) s_start[tid] = s_cnt[tid];
    __syncthreads();
    for (int off = 1; off < NB; off <<= 1) {
        int v = 0;
        if (tid < NB && tid >= off) v = s_start[tid - off];
        __syncthreads();
        if (tid < NB) s_start[tid] += v;
        __syncthreads();
    }
    if (tid < NB) {
        int ex = s_start[tid] - s_cnt[tid];
        s_start[tid] = ex;
        s_cur[tid] = ex;
    }
    __syncthreads();

#pragma unroll
    for (int k = 0; k < 4; k++) {
        if (cc[k] >= 0) {
            int d0 = 2 * cc[k];
            int b0 = d0 >> BSHIFT;
            int s0 = atomicAdd(&s_cur[b0], 1);
            s_items[s0] = ((unsigned)(d0 & BMASK) << 19) | (unsigned)rr[k];
            s_ibkt[s0] = (unsigned short)b0;
            int d1 = 2 * rr[k] + 1;
            int b1 = d1 >> BSHIFT;
            int s1 = atomicAdd(&s_cur[b1], 1);
            s_items[s1] = ((unsigned)(d1 & BMASK) << 19) | (unsigned)cc[k];
            s_ibkt[s1] = (unsigned short)b1;
        }
    }
    __syncthreads();

    if (tid < NB) s_gbase[tid] = atomicAdd(&bucket_cur[tid], s_cnt[tid]);
    __syncthreads();

    int tot = s_start[NB - 1] + s_cnt[NB - 1];
    for (int s = tid; s < tot; s += 1024) {
        int b = s_ibkt[s];
        int g = s_gbase[b] + (s - s_start[b]);
        binned[g] = s_items[s];
    }
}

// ---------------------------------------------------------------------------
// K3: CSR finalize per bucket, all fine-grained work in LDS.
// ---------------------------------------------------------------------------
__global__ void csr_kernel(const unsigned int* __restrict__ binned,
                           const int* __restrict__ bucket_base,
                           int* __restrict__ offs,
                           int* __restrict__ entries) {
    __shared__ int s_deg[2048];
    __shared__ int s_cur[2048];
    __shared__ int s_pair[1024];

    int t = threadIdx.x;
    int b = blockIdx.x;
    if (b == 0 && t == 0) offs[DSPACE] = 2 * N_EDGES;

    int ebase = bucket_base[b];
    int eend = bucket_base[b + 1];

    s_deg[t] = 0;
    s_deg[t + 1024] = 0;
    __syncthreads();

    for (int p = ebase + t; p < eend; p += 1024)
        atomicAdd(&s_deg[binned[p] >> 19], 1);
    __syncthreads();

    int d0 = s_deg[2 * t], d1 = s_deg[2 * t + 1];
    s_pair[t] = d0 + d1;
    __syncthreads();
    for (int off = 1; off < 1024; off <<= 1) {
        int v = (t >= off) ? s_pair[t - off] : 0;
        __syncthreads();
        s_pair[t] += v;
        __syncthreads();
    }
    int pex = s_pair[t] - (d0 + d1);
    s_cur[2 * t] = pex;
    s_cur[2 * t + 1] = pex + d0;

    int dest0 = b * 2048 + 2 * t;
    if (dest0 < DSPACE) offs[dest0] = ebase + pex;
    if (dest0 + 1 < DSPACE) offs[dest0 + 1] = ebase + pex + d0;
    __syncthreads();

    for (int p = ebase + t; p < eend; p += 1024) {
        unsigned int it = binned[p];
        int dl = it >> 19;
        int other = it & 0x7FFFF;
        int pos = atomicAdd(&s_cur[dl], 1);
        entries[ebase + pos] = other;
    }
}

// ---------------------------------------------------------------------------
// Final edge network -> out  (single-line gathers from padded rows)
// ---------------------------------------------------------------------------
__global__ void edge_kernel(const int* __restrict__ row,
                            const int* __restrict__ col,
                            const float* __restrict__ xrow,  // [Npad*16]
                            const float* __restrict__ e1_w,
                            const float* __restrict__ e1_b,
                            const float* __restrict__ e2_w,
                            const float* __restrict__ e2_b,
                            float* __restrict__ out) {
    __shared__ float s_e1w[20 * HID];
    __shared__ float s_e1b[HID];
    __shared__ float s_e2w[HID];
    __shared__ float s_e2b;
    int tid = threadIdx.x;
    if (tid < 160) s_e1w[tid] = e1_w[tid];
    else if (tid < 168) s_e1b[tid - 160] = e1_b[tid - 160];
    else if (tid < 176) s_e2w[tid - 168] = e2_w[tid - 168];
    else if (tid == 176) s_e2b = e2_b[0];
    __syncthreads();

    int i = blockIdx.x * blockDim.x + tid;
    if (i >= N_EDGES) return;

    int r = row[i], c = col[i];
    const float4* rp = (const float4*)xrow;
    float4 a0 = rp[4 * c], a1 = rp[4 * c + 1];
    float2 ab = *(const float2*)(xrow + (size_t)c * ROWF + 8);
    float4 b0 = rp[4 * r], b1 = rp[4 * r + 1];
    float2 bb = *(const float2*)(xrow + (size_t)r * ROWF + 8);
    float a[FDIM] = {a0.x, a0.y, a0.z, a0.w, a1.x, a1.y, a1.z, a1.w, ab.x, ab.y};
    float bf[FDIM] = {b0.x, b0.y, b0.z, b0.w, b1.x, b1.y, b1.z, b1.w, bb.x, bb.y};

    float dot = s_e2b;
#pragma unroll
    for (int j = 0; j < HID; j++) {
        float v = s_e1b[j];
#pragma unroll
        for (int k = 0; k < FDIM; k++) v += a[k] * s_e1w[k * HID + j];
#pragma unroll
        for (int k = 0; k < FDIM; k++) v += bf[k] * s_e1w[(FDIM + k) * HID + j];
        dot += fast_tanh(v) * s_e2w[j];
    }
    out[i] = fast_sigmoid(dot);
}

// ---------------------------------------------------------------------------
// Fused edge+gather+node network; 64 B-row gathers; LDS-staged full-line writes.
// ---------------------------------------------------------------------------
__global__ void node_kernel(const float* __restrict__ xrow,   // [Npad*16] (read)
                            const int* __restrict__ offs,     // [D+1]
                            const int* __restrict__ entries,  // [2E]
                            const float* __restrict__ e1_w,
                            const float* __restrict__ e1_b,
                            const float* __restrict__ e2_w,
                            const float* __restrict__ e2_b,
                            const float* __restrict__ n1_w,
                            const float* __restrict__ n1_b,
                            const float* __restrict__ n2_w,
                            const float* __restrict__ n2_b,
                            float* __restrict__ xnext) {      // [Npad*16] (write)
    __shared__ float s_e1w[20 * HID];
    __shared__ float s_e1b[HID];
    __shared__ float s_e2w[HID];
    __shared__ float s_e2b;
    __shared__ float s_n1w[30 * HID];
    __shared__ float s_n1b[HID];
    __shared__ float s_n2w[HID * HID];
    __shared__ float s_n2b[HID];
    __shared__ float s_out[256 * 17];
    int tid = threadIdx.x;
    if (tid < 160) s_e1w[tid] = e1_w[tid];
    else if (tid < 168) s_e1b[tid - 160] = e1_b[tid - 160];
    else if (tid < 176) s_e2w[tid - 168] = e2_w[tid - 168];
    else if (tid == 176) s_e2b = e2_b[0];
    if (tid < 240) s_n1w[tid] = n1_w[tid];
    else if (tid < 248) s_n1b[tid - 240] = n1_b[tid - 240];
    if (tid < 64) s_n2w[tid] = n2_w[tid];
    else if (tid < 72) s_n2b[tid - 64] = n2_b[tid - 64];
    __syncthreads();

    int n = blockIdx.x * 256 + tid;
    int lb = tid * 17;
    const float4* rp = (const float4*)xrow;

    if (n < N_NODES) {
        float4 sa0 = rp[4 * n], sa1 = rp[4 * n + 1];
        float2 sb = *(const float2*)(xrow + (size_t)n * ROWF + 8);
        float xn[FDIM] = {sa0.x, sa0.y, sa0.z, sa0.w, sa1.x, sa1.y, sa1.z, sa1.w, sb.x, sb.y};

        float u_self[HID], v_self[HID];
#pragma unroll
        for (int j = 0; j < HID; j++) {
            float u = 0.f, v = 0.f;
#pragma unroll
            for (int k = 0; k < FDIM; k++) {
                u += xn[k] * s_e1w[k * HID + j];
                v += xn[k] * s_e1w[(FDIM + k) * HID + j];
            }
            u_self[j] = u; v_self[j] = v;
        }

        float mi[FDIM], mo[FDIM];
#pragma unroll
        for (int k = 0; k < FDIM; k++) { mi[k] = 0.f; mo[k] = 0.f; }

        int base2 = 2 * n;
        int s0 = offs[base2], e0 = offs[base2 + 1], e1 = offs[base2 + 2];

        // mi: n is col; other = row (bottom half of e1_w for other)
        for (int p = s0; p < e0; p++) {
            int o = entries[p];
            float4 q0 = rp[4 * o], q1 = rp[4 * o + 1];
            float2 qb = *(const float2*)(xrow + (size_t)o * ROWF + 8);
            float xo[8] = {q0.x, q0.y, q0.z, q0.w, q1.x, q1.y, q1.z, q1.w};
            float d = s_e2b;
#pragma unroll
            for (int j = 0; j < HID; j++) {
                float v = u_self[j] + s_e1b[j];
#pragma unroll
                for (int k = 0; k < 8; k++) v += xo[k] * s_e1w[(FDIM + k) * HID + j];
                v += qb.x * s_e1w[(FDIM + 8) * HID + j] + qb.y * s_e1w[(FDIM + 9) * HID + j];
                d += fast_tanh(v) * s_e2w[j];
            }
            float e = fast_sigmoid(d);
#pragma unroll
            for (int k = 0; k < 8; k++) mi[k] += xo[k] * e;
            mi[8] += qb.x * e; mi[9] += qb.y * e;
        }

        // mo: n is row; other = col (top half of e1_w for other)
        for (int p = e0; p < e1; p++) {
            int o = entries[p];
            float4 q0 = rp[4 * o], q1 = rp[4 * o + 1];
            float2 qb = *(const float2*)(xrow + (size_t)o * ROWF + 8);
            float xo[8] = {q0.x, q0.y, q0.z, q0.w, q1.x, q1.y, q1.z, q1.w};
            float d = s_e2b;
#pragma unroll
            for (int j = 0; j < HID; j++) {
                float v = v_self[j] + s_e1b[j];
#pragma unroll
                for (int k = 0; k < 8; k++) v += xo[k] * s_e1w[k * HID + j];
                v += qb.x * s_e1w[8 * HID + j] + qb.y * s_e1w[9 * HID + j];
                d += fast_tanh(v) * s_e2w[j];
            }
            float e = fast_sigmoid(d);
#pragma unroll
            for (int k = 0; k < 8; k++) mo[k] += xo[k] * e;
            mo[8] += qb.x * e; mo[9] += qb.y * e;
        }

        float h[HID];
#pragma unroll
        for (int j = 0; j < HID; j++) {
            float v = s_n1b[j];
#pragma unroll
            for (int k = 0; k < FDIM; k++) v += mi[k] * s_n1w[k * HID + j];
#pragma unroll
            for (int k = 0; k < FDIM; k++) v += mo[k] * s_n1w[(FDIM + k) * HID + j];
#pragma unroll
            for (int k = 0; k < FDIM; k++) v += xn[k] * s_n1w[(2 * FDIM + k) * HID + j];
            h[j] = fast_tanh(v);
        }
#pragma unroll
        for (int j = 0; j < HID; j++) {
            float v = s_n2b[j];
#pragma unroll
            for (int k = 0; k < HID; k++) v += h[k] * s_n2w[k * HID + j];
            s_out[lb + j] = fast_tanh(v);
        }
        s_out[lb + 8] = xn[8];
        s_out[lb + 9] = xn[9];
#pragma unroll
        for (int j = 10; j < 16; j++) s_out[lb + j] = 0.f;
    } else {
#pragma unroll
        for (int j = 0; j < 16; j++) s_out[lb + j] = 0.f;
    }
    __syncthreads();

    // full-line coalesced flush: 256 rows x 64 B = 16 KB contiguous
    float4* dst = (float4*)xnext + (size_t)blockIdx.x * 1024;
    for (int s4 = tid; s4 < 1024; s4 += 256) {
        int fb = s4 * 4, ni = fb >> 4, j = fb & 15;
        dst[s4] = make_float4(s_out[ni * 17 + j], s_out[ni * 17 + j + 1],
                              s_out[ni * 17 + j + 2], s_out[ni * 17 + j + 3]);
    }
}

// ---------------------------------------------------------------------------
extern "C" void kernel_launch(void* const* d_in, const int* in_sizes, int n_in,
                              void* d_out, int out_size, void* d_ws, size_t ws_size,
                              hipStream_t stream) {
    const float* x      = (const float*)d_in[0];
    const int*   eidx   = (const int*)d_in[1];
    const float* win_w  = (const float*)d_in[2];
    const float* win_b  = (const float*)d_in[3];
    const float* e1_w   = (const float*)d_in[4];
    const float* e1_b   = (const float*)d_in[5];
    const float* e2_w   = (const float*)d_in[6];
    const float* e2_b   = (const float*)d_in[7];
    const float* n1_w   = (const float*)d_in[8];
    const float* n1_b   = (const float*)d_in[9];
    const float* n2_w   = (const float*)d_in[10];
    const float* n2_b   = (const float*)d_in[11];
    float* out = (float*)d_out;

    const int* row = eidx;
    const int* col = eidx + N_EDGES;

    // Workspace layout (~100 MB).  xrow1 region doubles as `binned` (the
    // binned buffer is dead once csr_kernel finishes, before any xrow1 write).
    const size_t ROWS_SZ = (size_t)ROWS_PAD * ROWF;        // 8,003,584 floats
    float* xrow0 = (float*)d_ws;                           // 32 MB
    float* xrow1 = xrow0 + ROWS_SZ;                        // 32 MB (= binned)
    unsigned int* binned = (unsigned int*)xrow1;           // 2E uints = 32 MB
    int* entries = (int*)(xrow1 + ROWS_SZ);                // 2E = 32 MB
    int* offs        = entries + 2 * (size_t)N_EDGES;      // D+1 (+pad)
    int* g_cnt       = offs + DSPACE + 64;                 // 512
    int* bucket_base = g_cnt + NB;                         // 513 (+pad)
    int* bucket_cur  = bucket_base + NB + 64;              // 512

    const int BLK = 256;
    int edge_blocks = (N_EDGES + BLK - 1) / BLK;
    int chunk_blocks = (N_EDGES + 4095) / 4096;

    // --- CSR build (writes binned in xrow1 region, then consumes it) ---
    hipMemsetAsync(g_cnt, 0, NB * sizeof(int), stream);
    bucket_hist_kernel<<<chunk_blocks, 256, 0, stream>>>(row, col, g_cnt);
    bucket_scan_kernel<<<1, NB, 0, stream>>>(g_cnt, bucket_base, bucket_cur);
    bin_kernel<<<chunk_blocks, 1024, 0, stream>>>(row, col, bucket_cur, binned);
    csr_kernel<<<NB_USED, 1024, 0, stream>>>(binned, bucket_base, offs, entries);

    // --- input network ---
    input_kernel<<<NODE_BLOCKS, BLK, 0, stream>>>(x, win_w, win_b, xrow0);

    // --- message-passing iterations (ping-pong xrow) ---
    float* cur = xrow0;
    float* nxt = xrow1;
    for (int it = 0; it < 3; it++) {
        node_kernel<<<NODE_BLOCKS, BLK, 0, stream>>>(
            cur, offs, entries, e1_w, e1_b, e2_w, e2_b,
            n1_w, n1_b, n2_w, n2_b, nxt);
        float* t = cur; cur = nxt; nxt = t;
    }

    // --- final edge network -> out ---
    edge_kernel<<<edge_blocks, BLK, 0, stream>>>(
        row, col, cur, e1_w, e1_b, e2_w, e2_b, out);
}

// Round 7
// 1407.336 us; speedup vs baseline: 1.4562x; 1.4442x over previous
//
#include <hip/hip_runtime.h>
#include <hip/hip_fp16.h>
#include <math.h>

#define N_NODES 500000
#define N_EDGES 4000000
#define FDIM 10   // IN_DIM + HID
#define HID 8
#define ROWDW 8   // dwords per fp16 node row (32 B): [h01,h23,h45,h67,x01,pad*3]

// Dest space: interleaved, dest = 2*col (mi side) or 2*row+1 (mo side).
#define DSPACE (2 * N_NODES)
#define NB 512
#define BSHIFT 11
#define BMASK 2047
#define NB_USED ((DSPACE + BMASK) / 2048)   // 489

#define NODE_BLOCKS ((N_NODES + 255) / 256)     // 1954
#define ROWS_PAD (NODE_BLOCKS * 256)            // 500224

// ---------------------------------------------------------------------------
// Fast transcendentals (hw exp2/rcp; error ~1e-6 vs threshold 1.35e-2)
// ---------------------------------------------------------------------------
__device__ __forceinline__ float fast_tanh(float x) {
    float e = __builtin_amdgcn_exp2f(x * 2.885390082f);  // exp(2x)
    return 1.0f - 2.0f * __builtin_amdgcn_rcpf(e + 1.0f);
}
__device__ __forceinline__ float fast_sigmoid(float x) {
    float e = __builtin_amdgcn_exp2f(-1.442695041f * x); // exp(-x)
    return __builtin_amdgcn_rcpf(1.0f + e);
}

// fp16 pack/unpack through float bit-carriers
__device__ __forceinline__ float2 h2f2(float bits) {
    union { float f; __half2 h; } u; u.f = bits;
    return __half22float2(u.h);
}
__device__ __forceinline__ float f2h2(float a, float b) {
    union { float f; __half2 h; } u; u.h = __floats2half2_rn(a, b);
    return u.f;
}

// Load one fp16 node row (exactly one 64B-line touch: dwordx4 + dword)
__device__ __forceinline__ void load_row(const float* __restrict__ xrow, int idx,
                                         float* xo /*[10]*/) {
    const float* rp = xrow + ((size_t)idx << 3);
    float4 q = *(const float4*)rp;
    float qx = rp[4];
    float2 p0 = h2f2(q.x), p1 = h2f2(q.y), p2 = h2f2(q.z), p3 = h2f2(q.w), p4 = h2f2(qx);
    xo[0] = p0.x; xo[1] = p0.y; xo[2] = p1.x; xo[3] = p1.y;
    xo[4] = p2.x; xo[5] = p2.y; xo[6] = p3.x; xo[7] = p3.y;
    xo[8] = p4.x; xo[9] = p4.y;
}

// ---------------------------------------------------------------------------
// Input network: xrow[n] = fp16[tanh(x @ win_w + win_b), x, pad] (32 B row),
// staged in LDS (stride 9), flushed as full-line float4 stores.
// ---------------------------------------------------------------------------
__global__ void input_kernel(const float* __restrict__ x,
                             const float* __restrict__ win_w,
                             const float* __restrict__ win_b,
                             float* __restrict__ xrow) {
    __shared__ float s_out[256 * 9];
    int tid = threadIdx.x;
    int n = blockIdx.x * 256 + tid;
    float x0 = 0.f, x1 = 0.f;
    if (n < N_NODES) { x0 = x[2 * n]; x1 = x[2 * n + 1]; }
    float h[HID];
#pragma unroll
    for (int j = 0; j < HID; j++)
        h[j] = fast_tanh(x0 * win_w[j] + x1 * win_w[HID + j] + win_b[j]);
    int lb = tid * 9;
    s_out[lb + 0] = f2h2(h[0], h[1]);
    s_out[lb + 1] = f2h2(h[2], h[3]);
    s_out[lb + 2] = f2h2(h[4], h[5]);
    s_out[lb + 3] = f2h2(h[6], h[7]);
    s_out[lb + 4] = f2h2(x0, x1);
    s_out[lb + 5] = 0.f; s_out[lb + 6] = 0.f; s_out[lb + 7] = 0.f;
    __syncthreads();
    float4* dst = (float4*)xrow + (size_t)blockIdx.x * 512;
    for (int s4 = tid; s4 < 512; s4 += 256) {
        int fb = s4 * 4, ni = fb >> 3, j = fb & 7;
        dst[s4] = make_float4(s_out[ni * 9 + j], s_out[ni * 9 + j + 1],
                              s_out[ni * 9 + j + 2], s_out[ni * 9 + j + 3]);
    }
}

// ---------------------------------------------------------------------------
// K0: bucket histogram, LDS-staged.
// ---------------------------------------------------------------------------
__global__ void bucket_hist_kernel(const int* __restrict__ row,
                                   const int* __restrict__ col,
                                   int* __restrict__ g_cnt) {
    __shared__ int s_cnt[NB];
    int tid = threadIdx.x;
    for (int i = tid; i < NB; i += 256) s_cnt[i] = 0;
    __syncthreads();
    int base = blockIdx.x * 4096;
#pragma unroll
    for (int k = 0; k < 16; k++) {
        int e = base + k * 256 + tid;
        if (e < N_EDGES) {
            int c = col[e], r = row[e];
            atomicAdd(&s_cnt[(2 * c) >> BSHIFT], 1);
            atomicAdd(&s_cnt[(2 * r + 1) >> BSHIFT], 1);
        }
    }
    __syncthreads();
    for (int i = tid; i < NB; i += 256) {
        int v = s_cnt[i];
        if (v) atomicAdd(&g_cnt[i], v);
    }
}

// ---------------------------------------------------------------------------
// K1: exclusive scan of bucket counts.
// ---------------------------------------------------------------------------
__global__ void bucket_scan_kernel(const int* __restrict__ g_cnt,
                                   int* __restrict__ bucket_base,
                                   int* __restrict__ bucket_cur) {
    __shared__ int s[NB];
    int t = threadIdx.x;
    int c = g_cnt[t];
    s[t] = c;
    __syncthreads();
    for (int off = 1; off < NB; off <<= 1) {
        int v = (t >= off) ? s[t - off] : 0;
        __syncthreads();
        s[t] += v;
        __syncthreads();
    }
    int ex = s[t] - c;
    bucket_base[t] = ex;
    bucket_cur[t] = ex;
    if (t == NB - 1) bucket_base[NB] = s[t];
}

// ---------------------------------------------------------------------------
// K2: binning into bucket-ordered staging (LDS), coalesced flush.
// ---------------------------------------------------------------------------
__global__ void bin_kernel(const int* __restrict__ row,
                           const int* __restrict__ col,
                           int* __restrict__ bucket_cur,
                           unsigned int* __restrict__ binned) {
    __shared__ int s_cnt[NB];
    __shared__ int s_start[NB];
    __shared__ int s_cur[NB];
    __shared__ int s_gbase[NB];
    __shared__ unsigned int s_items[8192];
    __shared__ unsigned short s_ibkt[8192];

    int tid = threadIdx.x;
    if (tid < NB) s_cnt[tid] = 0;
    __syncthreads();

    int base = blockIdx.x * 4096;
    int cc[4], rr[4];
#pragma unroll
    for (int k = 0; k < 4; k++) {
        int e = base + k * 1024 + tid;
        bool ok = (e < N_EDGES);
        cc[k] = ok ? col[e] : -1;
        rr[k] = ok ? row[e] : -1;
        if (ok) {
            atomicAdd(&s_cnt[(2 * cc[k]) >> BSHIFT], 1);
            atomicAdd(&s_cnt[(2 * rr[k] + 1) >> BSHIFT], 1);
        }
    }
    __syncthreads();

    if (tid < NB) s_start[tid] = s_cnt[tid];
    __syncthreads();
    for (int off = 1; off < NB; off <<= 1) {
        int v = 0;
        if (tid < NB && tid >= off) v = s_start[tid - off];
        __syncthreads();
        if (tid < NB) s_start[tid] += v;
        __syncthreads();
    }
    if (tid < NB) {
        int ex = s_start[tid] - s_cnt[tid];
        s_start[tid] = ex;
        s_cur[tid] = ex;
    }
    __syncthreads();

#pragma unroll
    for (int k = 0; k < 4; k++) {
        if (cc[k] >= 0) {
            int d0 = 2 * cc[k];
            int b0 = d0 >> BSHIFT;
            int s0 = atomicAdd(&s_cur[b0], 1);
            s_items[s0] = ((unsigned)(d0 & BMASK) << 19) | (unsigned)rr[k];
            s_ibkt[s0] = (unsigned short)b0;
            int d1 = 2 * rr[k] + 1;
            int b1 = d1 >> BSHIFT;
            int s1 = atomicAdd(&s_cur[b1], 1);
            s_items[s1] = ((unsigned)(d1 & BMASK) << 19) | (unsigned)cc[k];
            s_ibkt[s1] = (unsigned short)b1;
        }
    }
    __syncthreads();

    if (tid < NB) s_gbase[tid] = atomicAdd(&bucket_cur[tid], s_cnt[tid]);
    __syncthreads();

    int tot = s_start[NB - 1] + s_cnt[NB - 1];
    for (int s = tid; s < tot; s += 1024) {
        int b = s_ibkt[s];
        int g = s_gbase[b] + (s - s_start[b]);
        binned[g] = s_items[s];
    }
}

// ---------------------------------------------------------------------------
// K3: CSR finalize per bucket, all fine-grained work in LDS.
// ---------------------------------------------------------------------------
__global__ void csr_kernel(const unsigned int* __restrict__ binned,
                           const int* __restrict__ bucket_base,
                           int* __restrict__ offs,
                           int* __restrict__ entries) {
    __shared__ int s_deg[2048];
    __shared__ int s_cur[2048];
    __shared__ int s_pair[1024];

    int t = threadIdx.x;
    int b = blockIdx.x;
    if (b == 0 && t == 0) offs[DSPACE] = 2 * N_EDGES;

    int ebase = bucket_base[b];
    int eend = bucket_base[b + 1];

    s_deg[t] = 0;
    s_deg[t + 1024] = 0;
    __syncthreads();

    for (int p = ebase + t; p < eend; p += 1024)
        atomicAdd(&s_deg[binned[p] >> 19], 1);
    __syncthreads();

    int d0 = s_deg[2 * t], d1 = s_deg[2 * t + 1];
    s_pair[t] = d0 + d1;
    __syncthreads();
    for (int off = 1; off < 1024; off <<= 1) {
        int v = (t >= off) ? s_pair[t - off] : 0;
        __syncthreads();
        s_pair[t] += v;
        __syncthreads();
    }
    int pex = s_pair[t] - (d0 + d1);
    s_cur[2 * t] = pex;
    s_cur[2 * t + 1] = pex + d0;

    int dest0 = b * 2048 + 2 * t;
    if (dest0 < DSPACE) offs[dest0] = ebase + pex;
    if (dest0 + 1 < DSPACE) offs[dest0 + 1] = ebase + pex + d0;
    __syncthreads();

    for (int p = ebase + t; p < eend; p += 1024) {
        unsigned int it = binned[p];
        int dl = it >> 19;
        int other = it & 0x7FFFF;
        int pos = atomicAdd(&s_cur[dl], 1);
        entries[ebase + pos] = other;
    }
}

// ---------------------------------------------------------------------------
// Final edge network -> out  (fp16 single-line gathers)
// ---------------------------------------------------------------------------
__global__ void edge_kernel(const int* __restrict__ row,
                            const int* __restrict__ col,
                            const float* __restrict__ xrow,  // [Npad*8] fp16 rows
                            const float* __restrict__ e1_w,
                            const float* __restrict__ e1_b,
                            const float* __restrict__ e2_w,
                            const float* __restrict__ e2_b,
                            float* __restrict__ out) {
    __shared__ float s_e1w[20 * HID];
    __shared__ float s_e1b[HID];
    __shared__ float s_e2w[HID];
    __shared__ float s_e2b;
    int tid = threadIdx.x;
    if (tid < 160) s_e1w[tid] = e1_w[tid];
    else if (tid < 168) s_e1b[tid - 160] = e1_b[tid - 160];
    else if (tid < 176) s_e2w[tid - 168] = e2_w[tid - 168];
    else if (tid == 176) s_e2b = e2_b[0];
    __syncthreads();

    int i = blockIdx.x * blockDim.x + tid;
    if (i >= N_EDGES) return;

    int r = row[i], c = col[i];
    float a[FDIM], bf[FDIM];
    load_row(xrow, c, a);
    load_row(xrow, r, bf);

    float dot = s_e2b;
#pragma unroll
    for (int j = 0; j < HID; j++) {
        float v = s_e1b[j];
#pragma unroll
        for (int k = 0; k < FDIM; k++) v += a[k] * s_e1w[k * HID + j];
#pragma unroll
        for (int k = 0; k < FDIM; k++) v += bf[k] * s_e1w[(FDIM + k) * HID + j];
        dot += fast_tanh(v) * s_e2w[j];
    }
    out[i] = fast_sigmoid(dot);
}

// ---------------------------------------------------------------------------
// Fused edge+gather+node network; fp16 32 B-row gathers; LDS-staged writes.
// ---------------------------------------------------------------------------
__global__ void node_kernel(const float* __restrict__ xrow,   // [Npad*8] (read)
                            const int* __restrict__ offs,     // [D+1]
                            const int* __restrict__ entries,  // [2E]
                            const float* __restrict__ e1_w,
                            const float* __restrict__ e1_b,
                            const float* __restrict__ e2_w,
                            const float* __restrict__ e2_b,
                            const float* __restrict__ n1_w,
                            const float* __restrict__ n1_b,
                            const float* __restrict__ n2_w,
                            const float* __restrict__ n2_b,
                            float* __restrict__ xnext) {      // [Npad*8] (write)
    __shared__ float s_e1w[20 * HID];
    __shared__ float s_e1b[HID];
    __shared__ float s_e2w[HID];
    __shared__ float s_e2b;
    __shared__ float s_n1w[30 * HID];
    __shared__ float s_n1b[HID];
    __shared__ float s_n2w[HID * HID];
    __shared__ float s_n2b[HID];
    __shared__ float s_out[256 * 9];
    int tid = threadIdx.x;
    if (tid < 160) s_e1w[tid] = e1_w[tid];
    else if (tid < 168) s_e1b[tid - 160] = e1_b[tid - 160];
    else if (tid < 176) s_e2w[tid - 168] = e2_w[tid - 168];
    else if (tid == 176) s_e2b = e2_b[0];
    if (tid < 240) s_n1w[tid] = n1_w[tid];
    else if (tid < 248) s_n1b[tid - 240] = n1_b[tid - 240];
    if (tid < 64) s_n2w[tid] = n2_w[tid];
    else if (tid < 72) s_n2b[tid - 64] = n2_b[tid - 64];
    __syncthreads();

    int n = blockIdx.x * 256 + tid;
    int lb = tid * 9;

    if (n < N_NODES) {
        float xn[FDIM];
        load_row(xrow, n, xn);

        float u_self[HID], v_self[HID];
#pragma unroll
        for (int j = 0; j < HID; j++) {
            float u = 0.f, v = 0.f;
#pragma unroll
            for (int k = 0; k < FDIM; k++) {
                u += xn[k] * s_e1w[k * HID + j];
                v += xn[k] * s_e1w[(FDIM + k) * HID + j];
            }
            u_self[j] = u; v_self[j] = v;
        }

        float mi[FDIM], mo[FDIM];
#pragma unroll
        for (int k = 0; k < FDIM; k++) { mi[k] = 0.f; mo[k] = 0.f; }

        int base2 = 2 * n;
        int s0 = offs[base2], e0 = offs[base2 + 1], e1 = offs[base2 + 2];

        // mi: n is col; other = row (bottom half of e1_w for other)
        for (int p = s0; p < e0; p++) {
            int o = entries[p];
            float xo[FDIM];
            load_row(xrow, o, xo);
            float d = s_e2b;
#pragma unroll
            for (int j = 0; j < HID; j++) {
                float v = u_self[j] + s_e1b[j];
#pragma unroll
                for (int k = 0; k < FDIM; k++) v += xo[k] * s_e1w[(FDIM + k) * HID + j];
                d += fast_tanh(v) * s_e2w[j];
            }
            float e = fast_sigmoid(d);
#pragma unroll
            for (int k = 0; k < FDIM; k++) mi[k] += xo[k] * e;
        }

        // mo: n is row; other = col (top half of e1_w for other)
        for (int p = e0; p < e1; p++) {
            int o = entries[p];
            float xo[FDIM];
            load_row(xrow, o, xo);
            float d = s_e2b;
#pragma unroll
            for (int j = 0; j < HID; j++) {
                float v = v_self[j] + s_e1b[j];
#pragma unroll
                for (int k = 0; k < FDIM; k++) v += xo[k] * s_e1w[k * HID + j];
                d += fast_tanh(v) * s_e2w[j];
            }
            float e = fast_sigmoid(d);
#pragma unroll
            for (int k = 0; k < FDIM; k++) mo[k] += xo[k] * e;
        }

        float h[HID];
#pragma unroll
        for (int j = 0; j < HID; j++) {
            float v = s_n1b[j];
#pragma unroll
            for (int k = 0; k < FDIM; k++) v += mi[k] * s_n1w[k * HID + j];
#pragma unroll
            for (int k = 0; k < FDIM; k++) v += mo[k] * s_n1w[(FDIM + k) * HID + j];
#pragma unroll
            for (int k = 0; k < FDIM; k++) v += xn[k] * s_n1w[(2 * FDIM + k) * HID + j];
            h[j] = fast_tanh(v);
        }
        float H[HID];
#pragma unroll
        for (int j = 0; j < HID; j++) {
            float v = s_n2b[j];
#pragma unroll
            for (int k = 0; k < HID; k++) v += h[k] * s_n2w[k * HID + j];
            H[j] = fast_tanh(v);
        }
        s_out[lb + 0] = f2h2(H[0], H[1]);
        s_out[lb + 1] = f2h2(H[2], H[3]);
        s_out[lb + 2] = f2h2(H[4], H[5]);
        s_out[lb + 3] = f2h2(H[6], H[7]);
        s_out[lb + 4] = f2h2(xn[8], xn[9]);
        s_out[lb + 5] = 0.f; s_out[lb + 6] = 0.f; s_out[lb + 7] = 0.f;
    } else {
#pragma unroll
        for (int j = 0; j < 8; j++) s_out[lb + j] = 0.f;
    }
    __syncthreads();

    // full-line coalesced flush: 256 rows x 32 B = 8 KB contiguous
    float4* dst = (float4*)xnext + (size_t)blockIdx.x * 512;
    for (int s4 = tid; s4 < 512; s4 += 256) {
        int fb = s4 * 4, ni = fb >> 3, j = fb & 7;
        dst[s4] = make_float4(s_out[ni * 9 + j], s_out[ni * 9 + j + 1],
                              s_out[ni * 9 + j + 2], s_out[ni * 9 + j + 3]);
    }
}

// ---------------------------------------------------------------------------
extern "C" void kernel_launch(void* const* d_in, const int* in_sizes, int n_in,
                              void* d_out, int out_size, void* d_ws, size_t ws_size,
                              hipStream_t stream) {
    const float* x      = (const float*)d_in[0];
    const int*   eidx   = (const int*)d_in[1];
    const float* win_w  = (const float*)d_in[2];
    const float* win_b  = (const float*)d_in[3];
    const float* e1_w   = (const float*)d_in[4];
    const float* e1_b   = (const float*)d_in[5];
    const float* e2_w   = (const float*)d_in[6];
    const float* e2_b   = (const float*)d_in[7];
    const float* n1_w   = (const float*)d_in[8];
    const float* n1_b   = (const float*)d_in[9];
    const float* n2_w   = (const float*)d_in[10];
    const float* n2_b   = (const float*)d_in[11];
    float* out = (float*)d_out;

    const int* row = eidx;
    const int* col = eidx + N_EDGES;

    // Workspace layout (~100 MB):
    const size_t ROWS_SZ = (size_t)ROWS_PAD * ROWDW;       // 4,001,792 floats (16 MB)
    float* xrow0 = (float*)d_ws;                           // 16 MB
    float* xrow1 = xrow0 + ROWS_SZ;                        // 16 MB
    unsigned int* binned = (unsigned int*)(xrow1 + ROWS_SZ); // 2E uints = 32 MB
    int* entries = (int*)(binned + 2 * (size_t)N_EDGES);   // 2E = 32 MB
    int* offs        = entries + 2 * (size_t)N_EDGES;      // D+1 (+pad)
    int* g_cnt       = offs + DSPACE + 64;                 // 512
    int* bucket_base = g_cnt + NB;                         // 513 (+pad)
    int* bucket_cur  = bucket_base + NB + 64;              // 512

    const int BLK = 256;
    int edge_blocks = (N_EDGES + BLK - 1) / BLK;
    int chunk_blocks = (N_EDGES + 4095) / 4096;

    // --- CSR build ---
    hipMemsetAsync(g_cnt, 0, NB * sizeof(int), stream);
    bucket_hist_kernel<<<chunk_blocks, 256, 0, stream>>>(row, col, g_cnt);
    bucket_scan_kernel<<<1, NB, 0, stream>>>(g_cnt, bucket_base, bucket_cur);
    bin_kernel<<<chunk_blocks, 1024, 0, stream>>>(row, col, bucket_cur, binned);
    csr_kernel<<<NB_USED, 1024, 0, stream>>>(binned, bucket_base, offs, entries);

    // --- input network ---
    input_kernel<<<NODE_BLOCKS, BLK, 0, stream>>>(x, win_w, win_b, xrow0);

    // --- message-passing iterations (ping-pong xrow) ---
    float* cur = xrow0;
    float* nxt = xrow1;
    for (int it = 0; it < 3; it++) {
        node_kernel<<<NODE_BLOCKS, BLK, 0, stream>>>(
            cur, offs, entries, e1_w, e1_b, e2_w, e2_b,
            n1_w, n1_b, n2_w, n2_b, nxt);
        float* t = cur; cur = nxt; nxt = t;
    }

    // --- final edge network -> out ---
    edge_kernel<<<edge_blocks, BLK, 0, stream>>>(
        row, col, cur, e1_w, e1_b, e2_w, e2_b, out);
}